// Round 4
// baseline (3992.079 us; speedup 1.0000x reference)
//
#include <hip/hip_runtime.h>
#include <math.h>

#define Hh  8
#define Dd  512
#define SUB 256          // D/2
#define Nk  1024         // num_subkeys
#define TK  32           // top_k
#define Rr  8            // rows (b,c) per block
#define NT  256
#define W_ELEMS (65536 * 32)

__device__ __forceinline__ void f4_to_arr(float4 v, float* a) {
    a[0] = v.x; a[1] = v.y; a[2] = v.z; a[3] = v.w;
}

// Phase-1 arithmetic: single accumulator, sequential FUSED-FMA chain over the
// contraction dim in natural order (d = 0..255). This matches the per-element
// reduction of Eigen gebp / oneDNN brgemm / OpenBLAS sgemm microkernels (one
// accumulator per output element, k walked in order, fma = single rounding),
// i.e. the arithmetic of a jax-CPU or BLAS-backed numpy recompute.
// Tie-break everywhere: stable lowest-index (XLA TopK semantics).

__global__ __launch_bounds__(NT, 2)
void pk_kernel(const float* __restrict__ query,
               const float* __restrict__ keyl,
               const float* __restrict__ keyr,
               float* __restrict__ out)
{
    __shared__ float sc[Rr][Nk];          // 32 KB
    __shared__ float topv[2][Rr][TK];     // 2 KB
    __shared__ int   topi[2][Rr][TK];     // 2 KB

    const int bid  = blockIdx.x;
    const int h    = bid >> 10;           // h-major for L2 key locality
    const int tile = bid & 1023;
    const int bc0  = tile * Rr;
    const int t    = threadIdx.x;
    const int lane = t & 63;
    const int wave = t >> 6;

    for (int side = 0; side < 2; ++side) {
        const float* kbase = (side == 0 ? keyl : keyr) + (size_t)h * Nk * SUB;

        // ---- phase 1: sequential-FMA GEMV ----
        for (int g = 0; g < 4; ++g) {
            const float4* krow = (const float4*)(kbase + (size_t)(g * 256 + t) * SUB);
            for (int rq = 0; rq < 2; ++rq) {          // 4 rows in flight per pass
                const float4* qrow0 = (const float4*)(query +
                    ((size_t)(bc0 + rq * 4 + 0) * Hh + h) * Dd + side * SUB);
                const float4* qrow1 = (const float4*)(query +
                    ((size_t)(bc0 + rq * 4 + 1) * Hh + h) * Dd + side * SUB);
                const float4* qrow2 = (const float4*)(query +
                    ((size_t)(bc0 + rq * 4 + 2) * Hh + h) * Dd + side * SUB);
                const float4* qrow3 = (const float4*)(query +
                    ((size_t)(bc0 + rq * 4 + 3) * Hh + h) * Dd + side * SUB);
                const float4* qr_[4] = { qrow0, qrow1, qrow2, qrow3 };

                float acc[4] = {0.0f, 0.0f, 0.0f, 0.0f};
                for (int j = 0; j < SUB / 4; ++j) {   // 64 chunks of 4, in order
                    float kk[4];
                    f4_to_arr(krow[j], kk);
                    #pragma unroll
                    for (int rr = 0; rr < 4; ++rr) {
                        float qq[4];
                        f4_to_arr(qr_[rr][j], qq);    // wave-uniform -> scalar ld
                        // strictly sequential fused chain, d ascending
                        acc[rr] = fmaf(qq[0], kk[0], acc[rr]);
                        acc[rr] = fmaf(qq[1], kk[1], acc[rr]);
                        acc[rr] = fmaf(qq[2], kk[2], acc[rr]);
                        acc[rr] = fmaf(qq[3], kk[3], acc[rr]);
                    }
                }
                #pragma unroll
                for (int rr = 0; rr < 4; ++rr)
                    sc[rq * 4 + rr][g * 256 + t] = acc[rr];
            }
        }
        __syncthreads();

        // ---- phase 2: exact top-32 per row (stable lowest-index ties) ----
        for (int rr = 0; rr < 2; ++rr) {
            const int r = wave + rr * 4;
            float v[16];
            #pragma unroll
            for (int i = 0; i < 16; ++i) v[i] = sc[r][lane + 64 * i];
            for (int it = 0; it < TK; ++it) {
                float bv = v[0]; int bp = lane;
                #pragma unroll
                for (int i = 1; i < 16; ++i)
                    if (v[i] > bv) { bv = v[i]; bp = lane + 64 * i; }
                #pragma unroll
                for (int m = 1; m < 64; m <<= 1) {
                    float ov = __shfl_xor(bv, m, 64);
                    int   op = __shfl_xor(bp, m, 64);
                    if (ov > bv || (ov == bv && op < bp)) { bv = ov; bp = op; }
                }
                if (lane == it) { topv[side][r][it] = bv; topi[side][r][it] = bp; }
                if (lane == (bp & 63)) v[bp >> 6] = -INFINITY;
            }
        }
        __syncthreads();
    }

    // ---- phase 3: 32x32 product sums (exact fp32 adds), top-32, softmax ----
    for (int rr = 0; rr < 2; ++rr) {
        const int r = wave + rr * 4;
        float v[16];
        #pragma unroll
        for (int i = 0; i < 16; ++i) {
            int pos = lane + 64 * i;                  // pos = a*32 + b
            v[i] = __fadd_rn(topv[0][r][pos >> 5], topv[1][r][pos & 31]);
        }
        float m0 = 0.0f, wv = 0.0f; int wp = 0;
        for (int it = 0; it < TK; ++it) {
            float bv = v[0]; int bp = lane;
            #pragma unroll
            for (int i = 1; i < 16; ++i)
                if (v[i] > bv) { bv = v[i]; bp = lane + 64 * i; }
            #pragma unroll
            for (int m = 1; m < 64; m <<= 1) {
                float ov = __shfl_xor(bv, m, 64);
                int   op = __shfl_xor(bp, m, 64);
                if (ov > bv || (ov == bv && op < bp)) { bv = ov; bp = op; }
            }
            if (it == 0) m0 = bv;                     // rank 0 = max
            if (lane == it) { wv = bv; wp = bp; }
            if (lane == (bp & 63)) v[bp >> 6] = -INFINITY;
        }
        float e = (lane < TK) ? expf(wv - m0) : 0.0f;
        float s = e;
        #pragma unroll
        for (int m = 1; m < 64; m <<= 1) s += __shfl_xor(s, m, 64);
        if (lane < TK) {
            const int bc = bc0 + r;
            const size_t base = ((size_t)bc * Hh + h) * TK;
            const int a = wp >> 5;
            // reference quirk: product_indices[a*32+b] = l[a]*N + r[a]
            const int fl = topi[0][r][a] * Nk + topi[1][r][a];
            out[base + lane] = e / s;
            out[(size_t)W_ELEMS + base + lane] = (float)fl;
        }
    }
}

extern "C" void kernel_launch(void* const* d_in, const int* in_sizes, int n_in,
                              void* d_out, int out_size, void* d_ws, size_t ws_size,
                              hipStream_t stream)
{
    const float* query = (const float*)d_in[0];
    const float* keyl  = (const float*)d_in[1];
    const float* keyr  = (const float*)d_in[2];
    float* out = (float*)d_out;
    pk_kernel<<<dim3(8192), dim3(NT), 0, stream>>>(query, keyl, keyr, out);
}